// Round 8
// baseline (144.089 us; speedup 1.0000x reference)
//
#include <hip/hip_runtime.h>
#include <hip/hip_bf16.h>

// Problem: B=2, DIM=512, NUM_HEADS=1, tokens TOK=256 (16x16 window, w=1).
// R7 lesson: 1 block/CU + LDS-reduce barriers = 37 us of stall. This round:
// K1 (512 blocks x 256 thr = 2/CU): block = (b, channel-pair d0,d0+1).
//   GEMM: wave w owns g-slice [64w,64w+64); lane owns ONE g column and
//   accumulates all 6 qkv rows (q0,q1,k0,k1,v0,v1) over c=0..511 in VGPRs.
//   NO LDS reduce, NO partial sums -> ONE barrier total. Weights are
//   wave-uniform s_loads (8-c contiguous spans); x is coalesced b32 with
//   depth-8 register prefetch. Writes qs/ks/vs[g] directly (lane owns g).
//   Attention: R7's verified structure - waves (dl,gh), lane owns h-quad,
//   bias via 7-float register window from 61-entry stab (conflict-free),
//   additive g-half merge (scores bounded ~1.1, no max-subtraction).
// K2 (256 blocks x 256 thr): block = (b, 4 out-rows); wave = g-slice, lane =
//   one g; acc[4] over 512 c; ZERO LDS, ZERO barriers, depth-8 prefetch.
// Workspace: aout only (1 MB).

#define TOK   256
#define KDIM  512
#define LOG2E 1.4426950408889634f
#define SCALE 0.04419417382415922f   // 512^{-1/2}

// v_exp_f32 (base-2) — __exp2f collides with glibc math.h, use the builtin.
#define EXP2(x) __builtin_amdgcn_exp2f(x)

struct K1Smem {
    float stab[64];                    // rpb window table * log2e (61 used)
    float qs_[2][TOK];                 // q + bias
    float ks_[2][TOK];                 // (k + bias) * scale * log2e
    float vs_[2][TOK];                 // v + bias
    float lpart[2][TOK], apart[2][TOK];
};                                     // 10.5 KB

__global__ __launch_bounds__(256)
void qkv_attn(const float* __restrict__ x, const float* __restrict__ qkv_w,
              const float* __restrict__ qkv_b, const float* __restrict__ rpb,
              float* __restrict__ aout)
{
    __shared__ K1Smem sm;
    const int t    = threadIdx.x;
    const int w    = t >> 6;          // wave 0..3
    const int lane = t & 63;
    const int d0   = blockIdx.x * 2;  // channel pair
    const int b    = blockIdx.y;
    const int g    = w * 64 + lane;   // this lane's token column

    // bias table: stab[j] = rpb[mod(j-30, 961)] * log2e, j in 0..60
    if (t < 61) {
        const int rel = t - 30;
        sm.stab[t] = rpb[rel < 0 ? rel + 961 : rel] * LOG2E;
    }

    // ---- GEMM: 6 qkv rows for column g, K=512, depth-8 reg prefetch ----
    {
        const float* xb = x + (size_t)b * (KDIM * TOK) + g;
        // wave-uniform weight rows: q0,q1,k0,k1,v0,v1
        const float* wp[6];
        wp[0] = qkv_w + (size_t)(d0 + 0) * KDIM;
        wp[1] = qkv_w + (size_t)(d0 + 1) * KDIM;
        wp[2] = qkv_w + (size_t)(512 + d0 + 0) * KDIM;
        wp[3] = qkv_w + (size_t)(512 + d0 + 1) * KDIM;
        wp[4] = qkv_w + (size_t)(1024 + d0 + 0) * KDIM;
        wp[5] = qkv_w + (size_t)(1024 + d0 + 1) * KDIM;

        float acc[6] = {0.f, 0.f, 0.f, 0.f, 0.f, 0.f};
        float xv[8], xn[8];
#pragma unroll
        for (int u = 0; u < 8; ++u) xv[u] = xb[(size_t)u * TOK];
#pragma unroll 1
        for (int it = 0; it < 64; ++it) {
            const int cb = it * 8;
            if (it < 63) {
#pragma unroll
                for (int u = 0; u < 8; ++u)
                    xn[u] = xb[(size_t)(cb + 8 + u) * TOK];
            }
#pragma unroll
            for (int u = 0; u < 8; ++u) {
                const int c = cb + u;
#pragma unroll
                for (int e = 0; e < 6; ++e)
                    acc[e] = fmaf(wp[e][c], xv[u], acc[e]);   // s_load weights
            }
#pragma unroll
            for (int u = 0; u < 8; ++u) xv[u] = xn[u];
        }
        // lane owns g: direct conflict-free b32 stores
        sm.qs_[0][g] = acc[0] + qkv_b[d0 + 0];
        sm.qs_[1][g] = acc[1] + qkv_b[d0 + 1];
        sm.ks_[0][g] = (acc[2] + qkv_b[512 + d0 + 0]) * (SCALE * LOG2E);
        sm.ks_[1][g] = (acc[3] + qkv_b[512 + d0 + 1]) * (SCALE * LOG2E);
        sm.vs_[0][g] = acc[4] + qkv_b[1024 + d0 + 0];
        sm.vs_[1][g] = acc[5] + qkv_b[1024 + d0 + 1];
    }
    __syncthreads();   // the ONE barrier

    // ---- attention: wave = (dl channel, gh g-half); lane owns h-quad ----
    const int dl  = w & 1;
    const int gh  = w >> 1;
    const int h0  = lane * 4;
    const int rh0 = (lane >> 2) + 4 * (lane & 3);   // r(h0); r(h0+r)=rh0+r

    float q[4];
    {
        const float4 q4 = *(const float4*)&sm.qs_[dl][h0];
        q[0] = q4.x; q[1] = q4.y; q[2] = q4.z; q[3] = q4.w;
    }

    float l[4]  = {0.f, 0.f, 0.f, 0.f};
    float am[4] = {0.f, 0.f, 0.f, 0.f};
    const int pbeg = gh * 128;
#pragma unroll 2
    for (int p = pbeg; p < pbeg + 128; p += 4) {
        const float4 k4 = *(const float4*)&sm.ks_[dl][p];   // bcast
        const float4 v4 = *(const float4*)&sm.vs_[dl][p];   // bcast
        // 7-float bias window: bias[h0+r][p+j] = f[3 + r - j]
        const int i0 = rh0 + 30 - ((p >> 4) + (p & 15));
        float f[7];
#pragma unroll
        for (int k = 0; k < 7; ++k) f[k] = sm.stab[i0 - 3 + k];
#pragma unroll
        for (int r = 0; r < 4; ++r) {
            float e;
            e = EXP2(fmaf(q[r], k4.x, f[3 + r])); l[r] += e; am[r] = fmaf(e, v4.x, am[r]);
            e = EXP2(fmaf(q[r], k4.y, f[2 + r])); l[r] += e; am[r] = fmaf(e, v4.y, am[r]);
            e = EXP2(fmaf(q[r], k4.z, f[1 + r])); l[r] += e; am[r] = fmaf(e, v4.z, am[r]);
            e = EXP2(fmaf(q[r], k4.w, f[0 + r])); l[r] += e; am[r] = fmaf(e, v4.w, am[r]);
        }
    }

    // merge the two g-halves (additive: no max-subtraction, scores ~<=1.1)
    if (gh == 1) {
        *(float4*)&sm.lpart[dl][h0] = make_float4(l[0], l[1], l[2], l[3]);
        *(float4*)&sm.apart[dl][h0] = make_float4(am[0], am[1], am[2], am[3]);
    }
    __syncthreads();
    if (gh == 0) {
        const float4 lo = *(const float4*)&sm.lpart[dl][h0];
        const float4 ao = *(const float4*)&sm.apart[dl][h0];
        float4 o4;
        o4.x = (am[0] + ao.x) / (l[0] + lo.x);
        o4.y = (am[1] + ao.y) / (l[1] + lo.y);
        o4.z = (am[2] + ao.z) / (l[2] + lo.z);
        o4.w = (am[3] + ao.w) / (l[3] + lo.w);
        *(float4*)(aout + ((size_t)b * 512 + d0 + dl) * TOK + h0) = o4;
    }
}

// ---------------------------------------------------------------------------
// K2: proj rows o0..o0+3; wave = g-slice, lane = one g; acc[4] over 512 c.
// No LDS, no barriers. Weights wave-uniform s_loads; depth-8 prefetch.
// ---------------------------------------------------------------------------
__global__ __launch_bounds__(256)
void proj_fused(const float* __restrict__ aout, const float* __restrict__ proj_w,
                const float* __restrict__ proj_b, float* __restrict__ out)
{
    const int t    = threadIdx.x;
    const int w    = t >> 6;
    const int lane = t & 63;
    const int o0   = blockIdx.x * 4;
    const int b    = blockIdx.y;
    const int g    = w * 64 + lane;

    const float* ab = aout + (size_t)b * (KDIM * TOK) + g;
    const float* wp[4];
#pragma unroll
    for (int e = 0; e < 4; ++e)
        wp[e] = proj_w + (size_t)(o0 + e) * KDIM;

    float acc[4] = {0.f, 0.f, 0.f, 0.f};
    float av[8], an[8];
#pragma unroll
    for (int u = 0; u < 8; ++u) av[u] = ab[(size_t)u * TOK];
#pragma unroll 1
    for (int it = 0; it < 64; ++it) {
        const int cb = it * 8;
        if (it < 63) {
#pragma unroll
            for (int u = 0; u < 8; ++u)
                an[u] = ab[(size_t)(cb + 8 + u) * TOK];
        }
#pragma unroll
        for (int u = 0; u < 8; ++u) {
            const int c = cb + u;
#pragma unroll
            for (int e = 0; e < 4; ++e)
                acc[e] = fmaf(wp[e][c], av[u], acc[e]);     // s_load weights
        }
#pragma unroll
        for (int u = 0; u < 8; ++u) av[u] = an[u];
    }

#pragma unroll
    for (int e = 0; e < 4; ++e)
        out[((size_t)b * 512 + o0 + e) * TOK + g] = acc[e] + proj_b[o0 + e];
}

// ---------------------------------------------------------------------------
extern "C" void kernel_launch(void* const* d_in, const int* in_sizes, int n_in,
                              void* d_out, int out_size, void* d_ws, size_t ws_size,
                              hipStream_t stream)
{
    const float* x      = (const float*)d_in[0];   // [2][512][256]
    const float* qkv_w  = (const float*)d_in[1];   // [1536][512]
    const float* qkv_b  = (const float*)d_in[2];   // [1536]
    const float* proj_w = (const float*)d_in[3];   // [512][512]
    const float* proj_b = (const float*)d_in[4];   // [512]
    const float* rpb    = (const float*)d_in[5];   // [961]
    float* out  = (float*)d_out;                   // [2][512][256]
    float* aout = (float*)d_ws;                    // 262,144 floats (1 MB)

    // K1: fused qkv + attention. grid (d-pairs=256, b=2) = 512 blocks (2/CU)
    qkv_attn<<<dim3(256, 2), 256, 0, stream>>>(x, qkv_w, qkv_b, rpb, aout);

    // K2: fused proj + bias. grid (o-tiles=128, b=2) = 256 blocks (1/CU)
    proj_fused<<<dim3(128, 2), 256, 0, stream>>>(aout, proj_w, proj_b, out);
}